// Round 4
// baseline (977.907 us; speedup 1.0000x reference)
//
#include <hip/hip_runtime.h>
#include <hip/hip_bf16.h>
#include <stdint.h>

// ---------- helpers ----------
typedef __attribute__((ext_vector_type(8))) short bf16x8;
typedef __attribute__((ext_vector_type(4))) float f32x4;

__device__ __forceinline__ float bf16lo_to_f(uint32_t u) { return __uint_as_float(u << 16); }
__device__ __forceinline__ float bf16hi_to_f(uint32_t u) { return __uint_as_float(u & 0xffff0000u); }
__device__ __forceinline__ uint16_t f_to_bf16(float f) {
    uint32_t u = __float_as_uint(f);
    uint32_t r = u + 0x7fff + ((u >> 16) & 1);   // round-to-nearest-even
    return (uint16_t)(r >> 16);
}

// ---------- graph preprocessing ----------
__global__ void k_deg(const int* __restrict__ row, int* __restrict__ deg, int E) {
    int e = blockIdx.x * blockDim.x + threadIdx.x;
    if (e < E) atomicAdd(&deg[row[e]], 1);
}

// ----- 3-phase multi-block exclusive scan of deg -> offs/cursor -----
__global__ void k_psum(const int* __restrict__ deg, int* __restrict__ psum, int N) {
    __shared__ int sh[256];
    int t = threadIdx.x;
    int idx = blockIdx.x * 256 + t;
    sh[t] = idx < N ? deg[idx] : 0;
    __syncthreads();
    for (int o = 128; o > 0; o >>= 1) {
        if (t < o) sh[t] += sh[t + o];
        __syncthreads();
    }
    if (t == 0) psum[blockIdx.x] = sh[0];
}

__global__ void k_scanp(const int* __restrict__ psum, int* __restrict__ poff,
                        int* __restrict__ offs, int nb, int N) {
    __shared__ int sh[256];
    int t = threadIdx.x;
    int per = (nb + 255) >> 8;
    int base = t * per;
    int s = 0;
    for (int i = 0; i < per; i++) { int idx = base + i; if (idx < nb) s += psum[idx]; }
    sh[t] = s;
    __syncthreads();
    for (int o = 1; o < 256; o <<= 1) {
        int u = (t >= o) ? sh[t - o] : 0;
        __syncthreads();
        sh[t] += u;
        __syncthreads();
    }
    int run = sh[t] - s;
    for (int i = 0; i < per; i++) {
        int idx = base + i;
        if (idx < nb) { poff[idx] = run; run += psum[idx]; }
    }
    if (t == 255) offs[N] = sh[255];
}

__global__ void k_offs(const int* __restrict__ deg, const int* __restrict__ poff,
                       int* __restrict__ offs, int* __restrict__ cursor, int N) {
    __shared__ int sh[256];
    int t = threadIdx.x;
    int idx = blockIdx.x * 256 + t;
    int v = idx < N ? deg[idx] : 0;
    sh[t] = v;
    __syncthreads();
    for (int o = 1; o < 256; o <<= 1) {
        int u = (t >= o) ? sh[t - o] : 0;
        __syncthreads();
        sh[t] += u;
        __syncthreads();
    }
    if (idx < N) {
        int ex = poff[blockIdx.x] + sh[t] - v;
        offs[idx] = ex;
        cursor[idx] = ex;
    }
}

__global__ void k_disdiag(const int* __restrict__ deg, const int* __restrict__ batch,
                          const float* __restrict__ lam, float* __restrict__ dis,
                          float* __restrict__ diag, int N) {
    int n = blockIdx.x * blockDim.x + threadIdx.x;
    if (n < N) {
        int d = deg[n];
        dis[n] = d > 0 ? rsqrtf((float)d) : 0.f;
        diag[n] = 2.f / lam[batch[n]] - 1.f;
    }
}

__global__ void k_csr(const int* __restrict__ row, const int* __restrict__ col,
                      const int* __restrict__ batch, const float* __restrict__ lam,
                      const float* __restrict__ dis, int* __restrict__ cursor,
                      int2* __restrict__ csr, int E) {
    int e = blockIdx.x * blockDim.x + threadIdx.x;
    if (e < E) {
        int r = row[e], c = col[e];
        int pos = atomicAdd(&cursor[r], 1);
        float w = -2.f * dis[r] * dis[c] / lam[batch[r]];
        csr[pos] = make_int2(c, __float_as_int(w));
    }
}

// W [5][128][128] fp32 -> Wt bf16 [128 out][640 kk] (transposed, K-stacked)
__global__ void k_prepw(const float* __restrict__ W, uint16_t* __restrict__ Wt) {
    int i = blockIdx.x * blockDim.x + threadIdx.x;   // i = o*640 + kk
    if (i < 128 * 640) {
        int o = i / 640, kk = i % 640;
        Wt[i] = f_to_bf16(W[(size_t)kk * 128 + o]);
    }
}

// x fp32 [N][128] -> Txall slot 0 (row stride 640 bf16), vectorized (4B store)
__global__ void k_castx(const float* __restrict__ x, uint16_t* __restrict__ Tx, int N) {
    int i = blockIdx.x * blockDim.x + threadIdx.x;
    if (i < N * 64) {
        int n = i >> 6, f2 = i & 63;
        float2 v = ((const float2*)x)[(size_t)n * 64 + f2];
        uint32_t p = (uint32_t)f_to_bf16(v.x) | ((uint32_t)f_to_bf16(v.y) << 16);
        ((uint32_t*)Tx)[(size_t)n * 320 + f2] = p;
    }
}

// dst = alpha*(gather + diag*src) - (use_prev ? prev : 0), all slots in Txall (bf16)
// FEATURE-SLICED: one wave per (node, 32-feature slice). Quarter-waves process
// 4 edges concurrently (16 lanes x 4B = 64B line per edge). Slice varies slowest
// over blockIdx so the device-wide hot gather set at any instant is ~3.2MB ->
// L2-resident on every XCD (16x degree reuse at L2 latency).
__global__ void __launch_bounds__(256) k_lhat(uint16_t* __restrict__ Tx,
        const int* __restrict__ offs, const int2* __restrict__ csr,
        const float* __restrict__ diag, int N,
        int src, int dst, int prev, float alpha, int use_prev, int bps) {
    int slice = blockIdx.x / bps;
    int nidx = (blockIdx.x % bps) * 4 + (threadIdx.x >> 6);
    int lane = threadIdx.x & 63;
    if (nidx >= N) return;
    int q = lane >> 4, s16 = lane & 15;
    int beg = offs[nidx], end = offs[nidx + 1];
    const uint32_t* base = (const uint32_t*)Tx;   // row stride 320 uints
    int co = slice * 16 + s16;                    // uint32 offset within a slot
    int srcco = src * 64 + co;
    float ax = 0.f, ay = 0.f;
    for (int e0 = beg; e0 < end; e0 += 8) {
        int i0 = e0 + q, i1 = i0 + 4;
        bool k0 = i0 < end, k1 = i1 < end;
        int2 c0 = csr[k0 ? i0 : beg];
        int2 c1 = csr[k1 ? i1 : beg];
        float w0 = k0 ? __int_as_float(c0.y) : 0.f;
        float w1 = k1 ? __int_as_float(c1.y) : 0.f;
        uint32_t g0 = base[(size_t)c0.x * 320 + srcco];
        uint32_t g1 = base[(size_t)c1.x * 320 + srcco];
        ax += w0 * bf16lo_to_f(g0) + w1 * bf16lo_to_f(g1);
        ay += w0 * bf16hi_to_f(g0) + w1 * bf16hi_to_f(g1);
    }
    // reduce across the 4 quarter-waves
    ax += __shfl_xor(ax, 16); ax += __shfl_xor(ax, 32);
    ay += __shfl_xor(ay, 16); ay += __shfl_xor(ay, 32);

    float dg = diag[nidx];
    uint32_t sv = base[(size_t)nidx * 320 + srcco];
    ax = alpha * (ax + dg * bf16lo_to_f(sv));
    ay = alpha * (ay + dg * bf16hi_to_f(sv));
    if (use_prev) {
        uint32_t pv = base[(size_t)nidx * 320 + prev * 64 + co];
        ax -= bf16lo_to_f(pv);
        ay -= bf16hi_to_f(pv);
    }
    if (q == 0) {
        uint32_t outv = (uint32_t)f_to_bf16(ax) | ((uint32_t)f_to_bf16(ay) << 16);
        ((uint32_t*)Tx)[(size_t)nidx * 320 + dst * 64 + co] = outv;
    }
}

// ---------- GEMM: out[M,128] = relu(A[M,Kdim] @ Wt^T + bias), bf16 MFMA ----------
// BM=64, BN=128, BK=64 -> 782 blocks (breadth), LDS-transpose epilogue for
// fully-coalesced 16B/lane stores (kills partial-line write amplification).
#define BM 64
#define BK 64
#define LDT 72    // LDS row stride for As/Bs (bf16): 144B, 16B-aligned
#define LDC 132   // LDS row stride for C transpose (bf16): 264B

__global__ void __launch_bounds__(256) k_gemm(
        const uint16_t* __restrict__ A, int lda,
        const uint16_t* __restrict__ Bt,           // [128][Kdim]
        const float* __restrict__ bias,
        uint16_t* __restrict__ out, int ldo,
        uint16_t* __restrict__ out2,               // optional second dest (stride 640)
        int M, int Kdim) {
    __shared__ uint16_t smem[BM * LDT + 128 * LDT];   // 13824 u16 = 27.6KB
    uint16_t* As = smem;                 // 64 x 72
    uint16_t* Bs = smem + BM * LDT;      // 128 x 72
    uint16_t* Ct = smem;                 // reuse: 64 x 132 = 8448 <= 13824
    int t = threadIdx.x;
    int w = t >> 6, lane = t & 63;
    int row0 = blockIdx.x * BM;
    int mrow = (w >> 1) * 32, ncol = (w & 1) * 64;

    f32x4 acc[2][4];
#pragma unroll
    for (int i = 0; i < 2; i++)
#pragma unroll
        for (int j = 0; j < 4; j++) acc[i][j] = (f32x4){0.f, 0.f, 0.f, 0.f};

    for (int k0 = 0; k0 < Kdim; k0 += BK) {
        // stage A: 64 rows x 8 chunks = 512 chunks, 2 reps
#pragma unroll
        for (int rep = 0; rep < 2; rep++) {
            int d = rep * 256 + t;
            int r = d >> 3, kc = d & 7;
            int grow = row0 + r;
            bf16x8 va = {0, 0, 0, 0, 0, 0, 0, 0};
            if (grow < M) va = *(const bf16x8*)(A + (size_t)grow * lda + k0 + kc * 8);
            *(bf16x8*)(&As[r * LDT + kc * 8]) = va;
        }
        // stage B: 128 rows x 8 chunks = 1024 chunks, 4 reps
#pragma unroll
        for (int rep = 0; rep < 4; rep++) {
            int d = rep * 256 + t;
            int r = d >> 3, kc = d & 7;
            bf16x8 vb = *(const bf16x8*)(Bt + (size_t)r * Kdim + k0 + kc * 8);
            *(bf16x8*)(&Bs[r * LDT + kc * 8]) = vb;
        }
        __syncthreads();
#pragma unroll
        for (int ks = 0; ks < BK; ks += 32) {
            bf16x8 af[2], bfr[4];
#pragma unroll
            for (int i = 0; i < 2; i++) {
                int r = mrow + i * 16 + (lane & 15);
                af[i] = *(const bf16x8*)(&As[r * LDT + ks + (lane >> 4) * 8]);
            }
#pragma unroll
            for (int j = 0; j < 4; j++) {
                int c = ncol + j * 16 + (lane & 15);
                bfr[j] = *(const bf16x8*)(&Bs[c * LDT + ks + (lane >> 4) * 8]);
            }
#pragma unroll
            for (int i = 0; i < 2; i++)
#pragma unroll
                for (int j = 0; j < 4; j++)
                    acc[i][j] = __builtin_amdgcn_mfma_f32_16x16x32_bf16(af[i], bfr[j], acc[i][j], 0, 0, 0);
        }
        __syncthreads();
    }

    // epilogue: bias+relu -> bf16 into LDS (C layout), then coalesced 16B stores
#pragma unroll
    for (int j = 0; j < 4; j++) {
        int c = ncol + j * 16 + (lane & 15);
        float bv = bias[c];
#pragma unroll
        for (int i = 0; i < 2; i++) {
            int rloc = mrow + i * 16 + (lane >> 4) * 4;
#pragma unroll
            for (int r = 0; r < 4; r++) {
                float v = acc[i][j][r] + bv;
                v = v > 0.f ? v : 0.f;
                Ct[(rloc + r) * LDC + c] = f_to_bf16(v);
            }
        }
    }
    __syncthreads();
    // 64 rows x 128 cols x 2B = 16KB; 256 thr x 16B = 4KB/rep -> 4 reps
#pragma unroll
    for (int rep = 0; rep < 4; rep++) {
        int d = rep * 256 + t;
        int r = d >> 4, c8 = (d & 15) * 8;
        int grow = row0 + r;
        if (grow < M) {
            bf16x8 v = *(const bf16x8*)(&Ct[r * LDC + c8]);
            *(bf16x8*)(out + (size_t)grow * ldo + c8) = v;
            if (out2) *(bf16x8*)(out2 + (size_t)grow * 640 + c8) = v;
        }
    }
}

// ---------- pooling & final linear ----------
__global__ void k_count(const int* __restrict__ batch, int* __restrict__ counts,
                        int N, int B_) {
    int b = threadIdx.x;
    if (b >= B_) return;
    auto lb = [&](int v) {
        int lo = 0, hi = N;
        while (lo < hi) {
            int mid = (lo + hi) >> 1;
            if (batch[mid] < v) lo = mid + 1; else hi = mid;
        }
        return lo;
    };
    counts[b] = lb(b + 1) - lb(b);
}

__global__ void __launch_bounds__(128) k_pool(const uint16_t* __restrict__ h,
        const int* __restrict__ batch, float* __restrict__ pooled, int N, int CH) {
    int f = threadIdx.x;              // 0..127
    int n0 = blockIdx.x * CH;
    if (n0 >= N) return;
    int n1 = min(n0 + CH, N);
    float acc = 0.f;
    int cur = batch[n0];
    for (int n = n0; n < n1; ++n) {
        int b = batch[n];
        if (b != cur) { atomicAdd(&pooled[cur * 128 + f], acc); acc = 0.f; cur = b; }
        acc += __uint_as_float(((uint32_t)h[(size_t)n * 128 + f]) << 16);
    }
    atomicAdd(&pooled[cur * 128 + f], acc);
}

__global__ void k_final(const float* __restrict__ pooled, const int* __restrict__ counts,
                        const float* __restrict__ Wlin, const float* __restrict__ blin,
                        float* __restrict__ out, int B_, int C_) {
    int t = threadIdx.x;
    if (t < B_ * C_) {
        int b = t / C_, c = t % C_;
        float inv = 1.f / fmaxf((float)counts[b], 1.f);
        float acc = blin[c];
        for (int f = 0; f < 128; ++f) acc += pooled[b * 128 + f] * inv * Wlin[f * C_ + c];
        out[t] = acc;
    }
}

// ---------- launch ----------
extern "C" void kernel_launch(void* const* d_in, const int* in_sizes, int n_in,
                              void* d_out, int out_size, void* d_ws, size_t ws_size,
                              hipStream_t stream) {
    const float* x    = (const float*)d_in[0];
    const int*   edge = (const int*)d_in[1];
    const int*   batch= (const int*)d_in[2];
    const float* lam  = (const float*)d_in[3];
    const float* W1   = (const float*)d_in[4];
    const float* b1   = (const float*)d_in[5];
    const float* W2   = (const float*)d_in[6];
    const float* b2   = (const float*)d_in[7];
    const float* Wlin = (const float*)d_in[8];
    const float* blin = (const float*)d_in[9];
    const int E  = in_sizes[1] / 2;
    const int N  = in_sizes[2];
    const int B_ = in_sizes[3];
    const int* row = edge;
    const int* col = edge + E;

    char* ws = (char*)d_ws;
    size_t off = 0;
    auto take = [&](size_t bytes) -> char* {
        char* p = ws + off;
        off = (off + bytes + 255) & ~(size_t)255;
        return p;
    };
    uint16_t* Txall  = (uint16_t*)take((size_t)N * 640 * 2);   // 64 MB
    uint16_t* h      = (uint16_t*)take((size_t)N * 128 * 2);   // 12.8 MB
    int2*     csr    = (int2*)take((size_t)E * 8);             // 6.4 MB
    int*      deg    = (int*)take((size_t)N * 4);
    int*      offs   = (int*)take((size_t)(N + 1) * 4);
    int*      cursor = (int*)take((size_t)N * 4);
    float*    dis    = (float*)take((size_t)N * 4);
    float*    diag   = (float*)take((size_t)N * 4);
    uint16_t* Wt1    = (uint16_t*)take((size_t)128 * 640 * 2);
    uint16_t* Wt2    = (uint16_t*)take((size_t)128 * 640 * 2);
    float*    pooled = (float*)take((size_t)B_ * 128 * 4 + (size_t)B_ * 4);
    int*      counts = (int*)(pooled + (size_t)B_ * 128);
    const int nb = (N + 255) / 256;
    int*      psum   = (int*)take((size_t)nb * 4);
    int*      poff   = (int*)take((size_t)nb * 4);

    hipMemsetAsync(deg, 0, (size_t)N * 4, stream);
    hipMemsetAsync(pooled, 0, (size_t)B_ * 128 * 4 + (size_t)B_ * 4, stream);

    k_deg<<<(E + 255) / 256, 256, 0, stream>>>(row, deg, E);
    k_psum<<<nb, 256, 0, stream>>>(deg, psum, N);
    k_scanp<<<1, 256, 0, stream>>>(psum, poff, offs, nb, N);
    k_offs<<<nb, 256, 0, stream>>>(deg, poff, offs, cursor, N);
    k_disdiag<<<(N + 255) / 256, 256, 0, stream>>>(deg, batch, lam, dis, diag, N);
    k_csr<<<(E + 255) / 256, 256, 0, stream>>>(row, col, batch, lam, dis, cursor, csr, E);
    k_prepw<<<(128 * 640 + 255) / 256, 256, 0, stream>>>(W1, Wt1);
    k_prepw<<<(128 * 640 + 255) / 256, 256, 0, stream>>>(W2, Wt2);
    k_castx<<<(N * 64 + 255) / 256, 256, 0, stream>>>(x, Txall, N);

    const int bps = (N + 3) / 4;          // blocks per slice
    const int lblocks = bps * 4;          // 4 feature slices
    const int gblocks = (N + BM - 1) / BM;

    // layer 1: slots 0..4 = T_k(x)
    k_lhat<<<lblocks, 256, 0, stream>>>(Txall, offs, csr, diag, N, 0, 1, 0, 1.f, 0, bps);
    k_lhat<<<lblocks, 256, 0, stream>>>(Txall, offs, csr, diag, N, 1, 2, 0, 2.f, 1, bps);
    k_lhat<<<lblocks, 256, 0, stream>>>(Txall, offs, csr, diag, N, 2, 3, 1, 2.f, 1, bps);
    k_lhat<<<lblocks, 256, 0, stream>>>(Txall, offs, csr, diag, N, 3, 4, 2, 2.f, 1, bps);
    // h1 = relu(Txall @ W1stack + b1); dual-write into Txall slot 0 for layer 2
    k_gemm<<<gblocks, 256, 0, stream>>>(Txall, 640, Wt1, b1, h, 128, Txall, N, 640);

    // layer 2
    k_lhat<<<lblocks, 256, 0, stream>>>(Txall, offs, csr, diag, N, 0, 1, 0, 1.f, 0, bps);
    k_lhat<<<lblocks, 256, 0, stream>>>(Txall, offs, csr, diag, N, 1, 2, 0, 2.f, 1, bps);
    k_lhat<<<lblocks, 256, 0, stream>>>(Txall, offs, csr, diag, N, 2, 3, 1, 2.f, 1, bps);
    k_lhat<<<lblocks, 256, 0, stream>>>(Txall, offs, csr, diag, N, 3, 4, 2, 2.f, 1, bps);
    k_gemm<<<gblocks, 256, 0, stream>>>(Txall, 640, Wt2, b2, h, 128, (uint16_t*)nullptr, N, 640);

    k_count<<<1, 64, 0, stream>>>(batch, counts, N, B_);
    k_pool<<<(N + 127) / 128, 128, 0, stream>>>(h, batch, pooled, N, 128);
    k_final<<<1, 128, 0, stream>>>(pooled, counts, Wlin, blin, (float*)d_out, B_, 10);
}

// Round 5
// 623.455 us; speedup vs baseline: 1.5685x; 1.5685x over previous
//
#include <hip/hip_runtime.h>
#include <hip/hip_bf16.h>
#include <stdint.h>

// ---------- helpers ----------
typedef __attribute__((ext_vector_type(8))) short bf16x8;
typedef __attribute__((ext_vector_type(4))) float f32x4;

__device__ __forceinline__ float bf16lo_to_f(uint32_t u) { return __uint_as_float(u << 16); }
__device__ __forceinline__ float bf16hi_to_f(uint32_t u) { return __uint_as_float(u & 0xffff0000u); }
__device__ __forceinline__ uint16_t f_to_bf16(float f) {
    uint32_t u = __float_as_uint(f);
    uint32_t r = u + 0x7fff + ((u >> 16) & 1);   // round-to-nearest-even
    return (uint16_t)(r >> 16);
}

// ---------- graph preprocessing ----------
__global__ void k_deg(const int* __restrict__ row, int* __restrict__ deg, int E) {
    int e = blockIdx.x * blockDim.x + threadIdx.x;
    if (e < E) atomicAdd(&deg[row[e]], 1);
}

// ----- 3-phase multi-block exclusive scan of deg -> offs/cursor -----
__global__ void k_psum(const int* __restrict__ deg, int* __restrict__ psum, int N) {
    __shared__ int sh[256];
    int t = threadIdx.x;
    int idx = blockIdx.x * 256 + t;
    sh[t] = idx < N ? deg[idx] : 0;
    __syncthreads();
    for (int o = 128; o > 0; o >>= 1) {
        if (t < o) sh[t] += sh[t + o];
        __syncthreads();
    }
    if (t == 0) psum[blockIdx.x] = sh[0];
}

__global__ void k_scanp(const int* __restrict__ psum, int* __restrict__ poff,
                        int* __restrict__ offs, int nb, int N) {
    __shared__ int sh[256];
    int t = threadIdx.x;
    int per = (nb + 255) >> 8;
    int base = t * per;
    int s = 0;
    for (int i = 0; i < per; i++) { int idx = base + i; if (idx < nb) s += psum[idx]; }
    sh[t] = s;
    __syncthreads();
    for (int o = 1; o < 256; o <<= 1) {
        int u = (t >= o) ? sh[t - o] : 0;
        __syncthreads();
        sh[t] += u;
        __syncthreads();
    }
    int run = sh[t] - s;
    for (int i = 0; i < per; i++) {
        int idx = base + i;
        if (idx < nb) { poff[idx] = run; run += psum[idx]; }
    }
    if (t == 255) offs[N] = sh[255];
}

__global__ void k_offs(const int* __restrict__ deg, const int* __restrict__ poff,
                       int* __restrict__ offs, int* __restrict__ cursor, int N) {
    __shared__ int sh[256];
    int t = threadIdx.x;
    int idx = blockIdx.x * 256 + t;
    int v = idx < N ? deg[idx] : 0;
    sh[t] = v;
    __syncthreads();
    for (int o = 1; o < 256; o <<= 1) {
        int u = (t >= o) ? sh[t - o] : 0;
        __syncthreads();
        sh[t] += u;
        __syncthreads();
    }
    if (idx < N) {
        int ex = poff[blockIdx.x] + sh[t] - v;
        offs[idx] = ex;
        cursor[idx] = ex;
    }
}

__global__ void k_disdiag(const int* __restrict__ deg, const int* __restrict__ batch,
                          const float* __restrict__ lam, float* __restrict__ dis,
                          float* __restrict__ diag, int N) {
    int n = blockIdx.x * blockDim.x + threadIdx.x;
    if (n < N) {
        int d = deg[n];
        dis[n] = d > 0 ? rsqrtf((float)d) : 0.f;
        diag[n] = 2.f / lam[batch[n]] - 1.f;
    }
}

// fill CSR: csr[pos] = {col*320 (pre-scaled uint row index), w_edge bits}
__global__ void k_csr(const int* __restrict__ row, const int* __restrict__ col,
                      const int* __restrict__ batch, const float* __restrict__ lam,
                      const float* __restrict__ dis, int* __restrict__ cursor,
                      int2* __restrict__ csr, int E) {
    int e = blockIdx.x * blockDim.x + threadIdx.x;
    if (e < E) {
        int r = row[e], c = col[e];
        int pos = atomicAdd(&cursor[r], 1);
        float w = -2.f * dis[r] * dis[c] / lam[batch[r]];
        csr[pos] = make_int2(c * 320, __float_as_int(w));
    }
}

// W [5][128][128] fp32 -> Wt bf16 [128 out][640 kk] (transposed, K-stacked)
__global__ void k_prepw(const float* __restrict__ W, uint16_t* __restrict__ Wt) {
    int i = blockIdx.x * blockDim.x + threadIdx.x;   // i = o*640 + kk
    if (i < 128 * 640) {
        int o = i / 640, kk = i % 640;
        Wt[i] = f_to_bf16(W[(size_t)kk * 128 + o]);
    }
}

// x fp32 [N][128] -> Txall slot 0 (row stride 640 bf16), vectorized (4B store)
__global__ void k_castx(const float* __restrict__ x, uint16_t* __restrict__ Tx, int N) {
    int i = blockIdx.x * blockDim.x + threadIdx.x;
    if (i < N * 64) {
        int n = i >> 6, f2 = i & 63;
        float2 v = ((const float2*)x)[(size_t)n * 64 + f2];
        uint32_t p = (uint32_t)f_to_bf16(v.x) | ((uint32_t)f_to_bf16(v.y) << 16);
        ((uint32_t*)Tx)[(size_t)n * 320 + f2] = p;
    }
}

// dst = alpha*(gather + diag*src) - (use_prev ? prev : 0), all slots in Txall (bf16)
// one wave per node; lane handles features {2*lane, 2*lane+1}; csr.x pre-scaled c*320;
// 8-deep edge unroll for memory-level parallelism against L3 latency.
__global__ void __launch_bounds__(256) k_lhat(uint16_t* __restrict__ Tx,
        const int* __restrict__ offs, const int2* __restrict__ csr,
        const float* __restrict__ diag, int N,
        int src, int dst, int prev, float alpha, int use_prev) {
    int wid = (blockIdx.x * blockDim.x + threadIdx.x) >> 6;
    int lane = threadIdx.x & 63;
    if (wid >= N) return;
    const int n = wid;
    int beg = offs[n], end = offs[n + 1];
    float ax = 0.f, ay = 0.f;
    const uint32_t* base = (const uint32_t*)Tx;   // 2 bf16 per uint; row stride 320 uints
    int co = src * 64 + lane;
    int e = beg;
    for (; e + 8 <= end; e += 8) {
        int2 cc[8];
        uint32_t vv[8];
#pragma unroll
        for (int u = 0; u < 8; u++) cc[u] = csr[e + u];
#pragma unroll
        for (int u = 0; u < 8; u++) vv[u] = base[(size_t)(uint32_t)cc[u].x + co];
#pragma unroll
        for (int u = 0; u < 8; u++) {
            float w = __int_as_float(cc[u].y);
            ax += w * bf16lo_to_f(vv[u]);
            ay += w * bf16hi_to_f(vv[u]);
        }
    }
    for (; e < end; ++e) {
        int2 cw = csr[e];
        uint32_t v = base[(size_t)(uint32_t)cw.x + co];
        float w = __int_as_float(cw.y);
        ax += w * bf16lo_to_f(v);
        ay += w * bf16hi_to_f(v);
    }
    float dg = diag[n];
    uint32_t sv = base[(size_t)n * 320 + co];
    ax = alpha * (ax + dg * bf16lo_to_f(sv));
    ay = alpha * (ay + dg * bf16hi_to_f(sv));
    if (use_prev) {
        uint32_t pv = base[(size_t)n * 320 + prev * 64 + lane];
        ax -= bf16lo_to_f(pv);
        ay -= bf16hi_to_f(pv);
    }
    uint32_t outv = (uint32_t)f_to_bf16(ax) | ((uint32_t)f_to_bf16(ay) << 16);
    ((uint32_t*)Tx)[(size_t)n * 320 + dst * 64 + lane] = outv;
}

// ---------- GEMM: out[M,128] = relu(A[M,Kdim] @ Wt^T + bias), bf16 MFMA ----------
#define BM 128
#define BK 64
#define LDT 72    // LDS row stride As/Bs (bf16): 144B, 16B-aligned
#define LDC 132   // LDS row stride for C transpose (bf16)

__global__ void __launch_bounds__(256) k_gemm(
        const uint16_t* __restrict__ A, int lda,
        const uint16_t* __restrict__ Bt,           // [128][Kdim] (W transposed)
        const float* __restrict__ bias,
        uint16_t* __restrict__ out, int ldo,
        uint16_t* __restrict__ out2,               // optional second dest (stride 640)
        int M, int Kdim) {
    __shared__ uint16_t smem[BM * LDT + 128 * LDT];   // 36.9 KB
    uint16_t* As = smem;
    uint16_t* Bs = smem + BM * LDT;
    uint16_t* Ct = smem;                 // reuse: 128 x 132 = 16896 u16 <= 18432
    int t = threadIdx.x;
    int w = t >> 6, lane = t & 63;
    int row0 = blockIdx.x * BM;
    int mrow = (w >> 1) * 64, ncol = (w & 1) * 64;

    f32x4 acc[4][4];
#pragma unroll
    for (int i = 0; i < 4; i++)
#pragma unroll
        for (int j = 0; j < 4; j++) acc[i][j] = (f32x4){0.f, 0.f, 0.f, 0.f};

    for (int k0 = 0; k0 < Kdim; k0 += BK) {
#pragma unroll
        for (int rep = 0; rep < 4; rep++) {
            int d = rep * 256 + t;         // 1024 chunks of 8 bf16
            int r = d >> 3, kc = d & 7;
            int grow = row0 + r;
            bf16x8 va = {0, 0, 0, 0, 0, 0, 0, 0};
            if (grow < M) va = *(const bf16x8*)(A + (size_t)grow * lda + k0 + kc * 8);
            *(bf16x8*)(&As[r * LDT + kc * 8]) = va;
            bf16x8 vb = *(const bf16x8*)(Bt + (size_t)r * Kdim + k0 + kc * 8);
            *(bf16x8*)(&Bs[r * LDT + kc * 8]) = vb;
        }
        __syncthreads();
#pragma unroll
        for (int ks = 0; ks < BK; ks += 32) {
            bf16x8 af[4], bfr[4];
#pragma unroll
            for (int i = 0; i < 4; i++) {
                int r = mrow + i * 16 + (lane & 15);
                af[i] = *(const bf16x8*)(&As[r * LDT + ks + (lane >> 4) * 8]);
            }
#pragma unroll
            for (int j = 0; j < 4; j++) {
                int c = ncol + j * 16 + (lane & 15);
                bfr[j] = *(const bf16x8*)(&Bs[c * LDT + ks + (lane >> 4) * 8]);
            }
#pragma unroll
            for (int i = 0; i < 4; i++)
#pragma unroll
                for (int j = 0; j < 4; j++)
                    acc[i][j] = __builtin_amdgcn_mfma_f32_16x16x32_bf16(af[i], bfr[j], acc[i][j], 0, 0, 0);
        }
        __syncthreads();
    }

    // epilogue: bias+relu -> bf16 into LDS, then coalesced 16B/lane stores
#pragma unroll
    for (int j = 0; j < 4; j++) {
        int c = ncol + j * 16 + (lane & 15);
        float bv = bias[c];
#pragma unroll
        for (int i = 0; i < 4; i++) {
            int rloc = mrow + i * 16 + (lane >> 4) * 4;
#pragma unroll
            for (int r = 0; r < 4; r++) {
                float v = acc[i][j][r] + bv;
                v = v > 0.f ? v : 0.f;
                Ct[(rloc + r) * LDC + c] = f_to_bf16(v);
            }
        }
    }
    __syncthreads();
    // 128 rows x 16 chunks of 8 cols = 2048 chunks / 256 thr = 8 reps
#pragma unroll
    for (int rep = 0; rep < 8; rep++) {
        int d = rep * 256 + t;
        int r = d >> 4, c8 = (d & 15) * 8;
        int grow = row0 + r;
        if (grow < M) {
            bf16x8 v = *(const bf16x8*)(&Ct[r * LDC + c8]);
            *(bf16x8*)(out + (size_t)grow * ldo + c8) = v;
            if (out2) *(bf16x8*)(out2 + (size_t)grow * 640 + c8) = v;
        }
    }
}

// ---------- pooling & final linear ----------
__global__ void k_count(const int* __restrict__ batch, int* __restrict__ counts,
                        int N, int B_) {
    int b = threadIdx.x;
    if (b >= B_) return;
    auto lb = [&](int v) {
        int lo = 0, hi = N;
        while (lo < hi) {
            int mid = (lo + hi) >> 1;
            if (batch[mid] < v) lo = mid + 1; else hi = mid;
        }
        return lo;
    };
    counts[b] = lb(b + 1) - lb(b);
}

__global__ void __launch_bounds__(128) k_pool(const uint16_t* __restrict__ h,
        const int* __restrict__ batch, float* __restrict__ pooled, int N, int CH) {
    int f = threadIdx.x;              // 0..127
    int n0 = blockIdx.x * CH;
    if (n0 >= N) return;
    int n1 = min(n0 + CH, N);
    float acc = 0.f;
    int cur = batch[n0];
    for (int n = n0; n < n1; ++n) {
        int b = batch[n];
        if (b != cur) { atomicAdd(&pooled[cur * 128 + f], acc); acc = 0.f; cur = b; }
        acc += __uint_as_float(((uint32_t)h[(size_t)n * 128 + f]) << 16);
    }
    atomicAdd(&pooled[cur * 128 + f], acc);
}

__global__ void k_final(const float* __restrict__ pooled, const int* __restrict__ counts,
                        const float* __restrict__ Wlin, const float* __restrict__ blin,
                        float* __restrict__ out, int B_, int C_) {
    int t = threadIdx.x;
    if (t < B_ * C_) {
        int b = t / C_, c = t % C_;
        float inv = 1.f / fmaxf((float)counts[b], 1.f);
        float acc = blin[c];
        for (int f = 0; f < 128; ++f) acc += pooled[b * 128 + f] * inv * Wlin[f * C_ + c];
        out[t] = acc;
    }
}

// ---------- launch ----------
extern "C" void kernel_launch(void* const* d_in, const int* in_sizes, int n_in,
                              void* d_out, int out_size, void* d_ws, size_t ws_size,
                              hipStream_t stream) {
    const float* x    = (const float*)d_in[0];
    const int*   edge = (const int*)d_in[1];
    const int*   batch= (const int*)d_in[2];
    const float* lam  = (const float*)d_in[3];
    const float* W1   = (const float*)d_in[4];
    const float* b1   = (const float*)d_in[5];
    const float* W2   = (const float*)d_in[6];
    const float* b2   = (const float*)d_in[7];
    const float* Wlin = (const float*)d_in[8];
    const float* blin = (const float*)d_in[9];
    const int E  = in_sizes[1] / 2;
    const int N  = in_sizes[2];
    const int B_ = in_sizes[3];
    const int* row = edge;
    const int* col = edge + E;

    char* ws = (char*)d_ws;
    size_t off = 0;
    auto take = [&](size_t bytes) -> char* {
        char* p = ws + off;
        off = (off + bytes + 255) & ~(size_t)255;
        return p;
    };
    uint16_t* Txall  = (uint16_t*)take((size_t)N * 640 * 2);   // 64 MB
    uint16_t* h      = (uint16_t*)take((size_t)N * 128 * 2);   // 12.8 MB
    int2*     csr    = (int2*)take((size_t)E * 8);             // 6.4 MB
    int*      deg    = (int*)take((size_t)N * 4);
    int*      offs   = (int*)take((size_t)(N + 1) * 4);
    int*      cursor = (int*)take((size_t)N * 4);
    float*    dis    = (float*)take((size_t)N * 4);
    float*    diag   = (float*)take((size_t)N * 4);
    uint16_t* Wt1    = (uint16_t*)take((size_t)128 * 640 * 2);
    uint16_t* Wt2    = (uint16_t*)take((size_t)128 * 640 * 2);
    float*    pooled = (float*)take((size_t)B_ * 128 * 4 + (size_t)B_ * 4);
    int*      counts = (int*)(pooled + (size_t)B_ * 128);
    const int nb = (N + 255) / 256;
    int*      psum   = (int*)take((size_t)nb * 4);
    int*      poff   = (int*)take((size_t)nb * 4);

    hipMemsetAsync(deg, 0, (size_t)N * 4, stream);
    hipMemsetAsync(pooled, 0, (size_t)B_ * 128 * 4 + (size_t)B_ * 4, stream);

    k_deg<<<(E + 255) / 256, 256, 0, stream>>>(row, deg, E);
    k_psum<<<nb, 256, 0, stream>>>(deg, psum, N);
    k_scanp<<<1, 256, 0, stream>>>(psum, poff, offs, nb, N);
    k_offs<<<nb, 256, 0, stream>>>(deg, poff, offs, cursor, N);
    k_disdiag<<<(N + 255) / 256, 256, 0, stream>>>(deg, batch, lam, dis, diag, N);
    k_csr<<<(E + 255) / 256, 256, 0, stream>>>(row, col, batch, lam, dis, cursor, csr, E);
    k_prepw<<<(128 * 640 + 255) / 256, 256, 0, stream>>>(W1, Wt1);
    k_prepw<<<(128 * 640 + 255) / 256, 256, 0, stream>>>(W2, Wt2);
    k_castx<<<(N * 64 + 255) / 256, 256, 0, stream>>>(x, Txall, N);

    const int lblocks = (N + 3) / 4;     // 4 waves (nodes) per 256-thread block
    const int gblocks = (N + BM - 1) / BM;

    // layer 1: slots 0..4 = T_k(x)
    k_lhat<<<lblocks, 256, 0, stream>>>(Txall, offs, csr, diag, N, 0, 1, 0, 1.f, 0);
    k_lhat<<<lblocks, 256, 0, stream>>>(Txall, offs, csr, diag, N, 1, 2, 0, 2.f, 1);
    k_lhat<<<lblocks, 256, 0, stream>>>(Txall, offs, csr, diag, N, 2, 3, 1, 2.f, 1);
    k_lhat<<<lblocks, 256, 0, stream>>>(Txall, offs, csr, diag, N, 3, 4, 2, 2.f, 1);
    // h1 = relu(Txall @ W1stack + b1); dual-write into Txall slot 0 for layer 2
    k_gemm<<<gblocks, 256, 0, stream>>>(Txall, 640, Wt1, b1, h, 128, Txall, N, 640);

    // layer 2
    k_lhat<<<lblocks, 256, 0, stream>>>(Txall, offs, csr, diag, N, 0, 1, 0, 1.f, 0);
    k_lhat<<<lblocks, 256, 0, stream>>>(Txall, offs, csr, diag, N, 1, 2, 0, 2.f, 1);
    k_lhat<<<lblocks, 256, 0, stream>>>(Txall, offs, csr, diag, N, 2, 3, 1, 2.f, 1);
    k_lhat<<<lblocks, 256, 0, stream>>>(Txall, offs, csr, diag, N, 3, 4, 2, 2.f, 1);
    k_gemm<<<gblocks, 256, 0, stream>>>(Txall, 640, Wt2, b2, h, 128, (uint16_t*)nullptr, N, 640);

    k_count<<<1, 64, 0, stream>>>(batch, counts, N, B_);
    k_pool<<<(N + 127) / 128, 128, 0, stream>>>(h, batch, pooled, N, 128);
    k_final<<<1, 128, 0, stream>>>(pooled, counts, Wlin, blin, (float*)d_out, B_, 10);
}